// Round 3
// 560.125 us; speedup vs baseline: 1.0584x; 1.0584x over previous
//
#include <hip/hip_runtime.h>

// AFDChannelAttention on MI355X — fp32 in/out (x: [32,512,64,64] float32).
// rows BC=16384, L=4096, N_BASIS=64, R=0.9.
// proj = X*B^T via bf16 MFMA with hi/lo split of BOTH operands (3 chains,
// fp32-quality logits), softmax(|proj|), out = x + W*B (bf16 MFMA, fp32 add).
//
// v2 restructure (latency/issue-bound fix):
//  - GEMM1 split over K across the 4 waves (wave w: k in [w*1024,(w+1)*1024),
//    all 4 n-tiles). Removes the 4x-redundant x loads + f2bf conversions the
//    old n-split had (xp was wave-invariant). Partials reduced via LDS.
//  - Explicit 1-deep register prefetch of the x stream (old kernel had
//    VGPR_Count=32 -> zero prefetch depth, serialized on HBM latency).
//  - GEMM2 epilogue goes through a per-wave LDS tile so x-load/out-store are
//    f32x4 dense (2 VMEM/iter instead of 8 scalar).

typedef short s16x8 __attribute__((ext_vector_type(8)));
typedef float f32x4 __attribute__((ext_vector_type(4)));

#define MFMA16(a, b, c) __builtin_amdgcn_mfma_f32_16x16x32_bf16((a), (b), (c), 0, 0, 0)

#define L_DIM   4096
#define N_BASIS 64
#define BC      16384

__device__ __forceinline__ float bf2f(ushort u) {
    union { unsigned int i; float f; } v; v.i = ((unsigned int)u) << 16; return v.f;
}
__device__ __forceinline__ ushort f2bf(float f) {
    union { float f; unsigned int i; } v; v.f = f;
    unsigned int i = v.i;
    return (ushort)((i + 0x7FFFu + ((i >> 16) & 1u)) >> 16);   // RNE
}

// ---------------------------------------------------------------------------
// Kernel 1: Blaschke basis, pre-swizzled into MFMA B-operand fragment layout.
//  b1h/b1l (GEMM1, K=l, col=n): elem (n,l) at ((l/8)*64+n)*8 + l%8
//  b2h     (GEMM2, K=n, col=l): elem (n,l) at ((n/8)*4096+l)*8 + n%8
// ---------------------------------------------------------------------------
__global__ __launch_bounds__(256) void afd_basis_kernel(ushort* __restrict__ b1h,
                                                        ushort* __restrict__ b1l,
                                                        ushort* __restrict__ b2h) {
    int idx = blockIdx.x * 256 + threadIdx.x;      // 0 .. 64*4096-1
    int n = idx & 63;
    int l = idx >> 6;
    // t_l = 2pi*l/4095 (endpoint=True), theta_n = 2pi*n/64 (endpoint=False)
    double ph = 6.283185307179586 * ((double)l / 4095.0 - (double)n / 64.0);
    float c = cosf((float)ph);
    float rc = 0.9f * c;
    float B = 0.435889894354f * (1.0f - rc) / (1.81f - 2.0f * rc);
    ushort hi = f2bf(B);
    float lo = B - bf2f(hi);
    ushort lo16 = f2bf(lo);
    int i1 = ((l >> 3) * 64 + n) * 8 + (l & 7);
    b1h[i1] = hi;
    b1l[i1] = lo16;
    int i2 = ((n >> 3) * 4096 + l) * 8 + (n & 7);
    b2h[i2] = hi;
}

// ---------------------------------------------------------------------------
// Kernel 2: fused proj -> softmax -> attn -> add, 16 rows per block.
// 256 threads = 4 waves.
//  GEMM1: wave w owns k-quarter [w*1024, +1024), computes all 4 n-tiles.
//  GEMM2: wave w owns l-quarter [w*1024, +1024).
// ---------------------------------------------------------------------------
__global__ __launch_bounds__(256, 4) void afd_main_kernel(const float* __restrict__ x,
                                                          float* __restrict__ out,
                                                          const ushort* __restrict__ b1h,
                                                          const ushort* __restrict__ b1l,
                                                          const ushort* __restrict__ b2h) {
    __shared__ __align__(16) float  projp[4][16][68];   // [k-quarter][row][n]
    __shared__ float  red[16][16];
    __shared__ float  rowstat[16];
    __shared__ __align__(16) ushort wbf[16][64];
    __shared__ __align__(16) float  ctile[4][16][20];   // per-wave epilogue tile

    const int tid  = threadIdx.x;
    const int wave = tid >> 6;
    const int lane = tid & 63;
    const int l16  = lane & 15;
    const int q    = lane >> 4;
    const int rb   = blockIdx.x * 16;

    // ---------------- GEMM1: split-K across waves -------------------------
    // A-frag: lane holds x[rb+l16][wave*1024 + k0 + q*8 .. +7], hi/lo bf16.
    // B-frag: pre-swizzled b1h/b1l; tile t at +t*128 ushorts.
    const float*  xp  = x + (rb + l16) * L_DIM + wave * 1024 + q * 8;
    const ushort* bhp = b1h + wave * 65536 + l16 * 8 + q * 512;   // (wave*1024/8)*512
    const ushort* blp = b1l + wave * 65536 + l16 * 8 + q * 512;

    f32x4 acc[3][4];   // [chain hh/hl/lh][n-tile]
#pragma unroll
    for (int c = 0; c < 3; ++c)
#pragma unroll
        for (int t = 0; t < 4; ++t) acc[c][t] = (f32x4){0.f, 0.f, 0.f, 0.f};

    f32x4 cx0 = *(const f32x4*)(xp);
    f32x4 cx1 = *(const f32x4*)(xp + 4);
#pragma unroll 1
    for (int it = 0; it < 32; ++it) {
        const int k0 = it * 32;
        // 1-deep prefetch of the HBM x stream (guarded: last iter re-reads k0)
        const int kn = (it != 31) ? (k0 + 32) : k0;
        f32x4 nx0 = *(const f32x4*)(xp + kn);
        f32x4 nx1 = *(const f32x4*)(xp + kn + 4);

        s16x8 xh, xl;
#pragma unroll
        for (int j = 0; j < 4; ++j) {
            ushort h0 = f2bf(cx0[j]);
            xh[j] = (short)h0;
            xl[j] = (short)f2bf(cx0[j] - bf2f(h0));
            ushort h1 = f2bf(cx1[j]);
            xh[4 + j] = (short)h1;
            xl[4 + j] = (short)f2bf(cx1[j] - bf2f(h1));
        }
        const ushort* bh = bhp + (k0 << 6);
        const ushort* bl = blp + (k0 << 6);
#pragma unroll
        for (int t = 0; t < 4; ++t) {
            s16x8 vh = *(const s16x8*)(bh + t * 128);
            s16x8 vl = *(const s16x8*)(bl + t * 128);
            acc[0][t] = MFMA16(xh, vh, acc[0][t]);
            acc[1][t] = MFMA16(xh, vl, acc[1][t]);
            acc[2][t] = MFMA16(xl, vh, acc[2][t]);
        }
        cx0 = nx0; cx1 = nx1;
    }
    // C layout: col = lane&15 (= n within tile), row = q*4 + reg
#pragma unroll
    for (int t = 0; t < 4; ++t) {
        f32x4 p = acc[0][t] + (acc[1][t] + acc[2][t]);
#pragma unroll
        for (int r = 0; r < 4; ++r)
            projp[wave][q * 4 + r][t * 16 + l16] = p[r];
    }
    __syncthreads();

    // ---------------- softmax(|proj|) over n=64, per row ------------------
    {
        const int row = tid >> 4;       // 16 rows
        const int i   = tid & 15;       // 16 segments of 4 n each
        f32x4 s = *(const f32x4*)&projp[0][row][i * 4];
        s += *(const f32x4*)&projp[1][row][i * 4];
        s += *(const f32x4*)&projp[2][row][i * 4];
        s += *(const f32x4*)&projp[3][row][i * 4];
        float a0 = fabsf(s[0]), a1 = fabsf(s[1]);
        float a2 = fabsf(s[2]), a3 = fabsf(s[3]);
        red[row][i] = fmaxf(fmaxf(a0, a1), fmaxf(a2, a3));
        __syncthreads();
        if (tid < 16) {
            float rm = red[tid][0];
#pragma unroll
            for (int j = 1; j < 16; ++j) rm = fmaxf(rm, red[tid][j]);
            rowstat[tid] = rm;
        }
        __syncthreads();
        float rm = rowstat[row];
        float e0 = __expf(a0 - rm), e1 = __expf(a1 - rm);
        float e2 = __expf(a2 - rm), e3 = __expf(a3 - rm);
        red[row][i] = e0 + e1 + e2 + e3;
        __syncthreads();
        if (tid < 16) {
            float ss = red[tid][0];
#pragma unroll
            for (int j = 1; j < 16; ++j) ss += red[tid][j];
            rowstat[tid] = 1.0f / ss;
        }
        __syncthreads();
        float inv = rowstat[row];
        wbf[row][i * 4 + 0] = f2bf(e0 * inv);
        wbf[row][i * 4 + 1] = f2bf(e1 * inv);
        wbf[row][i * 4 + 2] = f2bf(e2 * inv);
        wbf[row][i * 4 + 3] = f2bf(e3 * inv);
    }
    __syncthreads();

    // ---------------- GEMM2: out = x + W * B (vectorized epilogue) --------
    s16x8 a0f = *(const s16x8*)&wbf[l16][q * 8];
    s16x8 a1f = *(const s16x8*)&wbf[l16][32 + q * 8];
    const f32x4 zero = {0.f, 0.f, 0.f, 0.f};
    const ushort* b2p = b2h + (q * 4096 + l16) * 8;
    const int erow = lane >> 2;        // 0..15: epilogue row
    const int el4  = (lane & 3) * 4;   // epilogue l sub-offset
    float* ct = &ctile[wave][0][0];

#pragma unroll 2
    for (int i = 0; i < 64; ++i) {
        const int l0 = wave * 1024 + i * 16;
        s16x8 b0  = *(const s16x8*)(b2p + (l0 << 3));
        s16x8 b1v = *(const s16x8*)(b2p + 131072 + (l0 << 3));   // n += 32
        f32x4 c = MFMA16(a0f, b0, zero);
        c = MFMA16(a1f, b1v, c);
        // C layout: col(l) = lane&15, row = q*4 + reg -> stage in LDS tile,
        // then each lane handles one row-quad dense (f32x4 load+store).
#pragma unroll
        for (int r = 0; r < 4; ++r)
            ct[(q * 4 + r) * 20 + l16] = c[r];
        f32x4 cc = *(const f32x4*)(ct + erow * 20 + el4);
        const int base = (rb + erow) * L_DIM + l0 + el4;
        f32x4 xv = *(const f32x4*)(x + base);
        *(f32x4*)(out + base) = xv + cc;
    }
}

// ---------------------------------------------------------------------------
extern "C" void kernel_launch(void* const* d_in, const int* in_sizes, int n_in,
                              void* d_out, int out_size, void* d_ws, size_t ws_size,
                              hipStream_t stream) {
    const float* x = (const float*)d_in[0];
    float* out = (float*)d_out;

    // workspace: 3 pre-swizzled basis arrays, 64*4096 bf16 each (512 KiB each)
    ushort* b1h = (ushort*)d_ws;
    ushort* b1l = b1h + (size_t)N_BASIS * L_DIM;
    ushort* b2h = b1l + (size_t)N_BASIS * L_DIM;

    // ws is re-poisoned before every launch -> rebuild basis every call
    afd_basis_kernel<<<(N_BASIS * L_DIM) / 256, 256, 0, stream>>>(b1h, b1l, b2h);
    afd_main_kernel<<<BC / 16, 256, 0, stream>>>(x, out, b1h, b1l, b2h);
}

// Round 4
// 523.336 us; speedup vs baseline: 1.1328x; 1.0703x over previous
//
#include <hip/hip_runtime.h>

// AFDChannelAttention on MI355X — fp32 in/out (x: [32,512,64,64] float32).
// rows BC=16384, L=4096, N_BASIS=64, R=0.9.
// proj = X*B^T via bf16 MFMA with hi/lo split of BOTH operands (3 chains,
// fp32-quality logits), softmax(|proj|), out = x + W*B (bf16 MFMA, fp32 add).
//
// v3: DRAM-efficiency restructure. v2 measured 2.08 TB/s effective HBM BW
// (26% of achievable) with all pipes idle — every x-load / out-store
// instruction touched 16 rows x 64B scattered across 256 KB. v3 makes every
// HBM instruction 1 KB contiguous:
//  - GEMM1: x staged through double-buffered LDS k-chunks (256 floats/row);
//    each wave stages 4 rows with one 1KB-contiguous f32x4 load per row.
//    Waves split each chunk's K 4 ways (no redundant loads/converts).
//    Raw s_barrier + lgkmcnt(0) only (no vmcnt drain) so next-chunk loads
//    stay in flight across the barrier.
//  - GEMM2: C staged in LDS ctile per 256-l chunk; cooperative epilogue,
//    each wave RMWs 4 rows with 1KB-contiguous loads/stores; chunk's x
//    prefetched at chunk top (hidden under MFMA phase).
//  - LDS 53.8 KB (union: GEMM1 xbuf+projp / GEMM2 ctile) -> 3 blocks/CU.

typedef short s16x8 __attribute__((ext_vector_type(8)));
typedef float f32x4 __attribute__((ext_vector_type(4)));

#define MFMA16(a, b, c) __builtin_amdgcn_mfma_f32_16x16x32_bf16((a), (b), (c), 0, 0, 0)

#define L_DIM   4096
#define N_BASIS 64
#define BC      16384

__device__ __forceinline__ float bf2f(ushort u) {
    union { unsigned int i; float f; } v; v.i = ((unsigned int)u) << 16; return v.f;
}
__device__ __forceinline__ ushort f2bf(float f) {
    union { float f; unsigned int i; } v; v.f = f;
    unsigned int i = v.i;
    return (ushort)((i + 0x7FFFu + ((i >> 16) & 1u)) >> 16);   // RNE
}

// ---------------------------------------------------------------------------
// Kernel 1: Blaschke basis, pre-swizzled into MFMA B-operand fragment layout.
//  b1h/b1l (GEMM1, K=l, col=n): elem (n,l) at ((l/8)*64+n)*8 + l%8
//  b2h     (GEMM2, K=n, col=l): elem (n,l) at ((n/8)*4096+l)*8 + n%8
// ---------------------------------------------------------------------------
__global__ __launch_bounds__(256) void afd_basis_kernel(ushort* __restrict__ b1h,
                                                        ushort* __restrict__ b1l,
                                                        ushort* __restrict__ b2h) {
    int idx = blockIdx.x * 256 + threadIdx.x;      // 0 .. 64*4096-1
    int n = idx & 63;
    int l = idx >> 6;
    // t_l = 2pi*l/4095 (endpoint=True), theta_n = 2pi*n/64 (endpoint=False)
    double ph = 6.283185307179586 * ((double)l / 4095.0 - (double)n / 64.0);
    float c = cosf((float)ph);
    float rc = 0.9f * c;
    float B = 0.435889894354f * (1.0f - rc) / (1.81f - 2.0f * rc);
    ushort hi = f2bf(B);
    float lo = B - bf2f(hi);
    ushort lo16 = f2bf(lo);
    int i1 = ((l >> 3) * 64 + n) * 8 + (l & 7);
    b1h[i1] = hi;
    b1l[i1] = lo16;
    int i2 = ((n >> 3) * 4096 + l) * 8 + (n & 7);
    b2h[i2] = hi;
}

// ---------------------------------------------------------------------------
// Kernel 2: fused proj -> softmax -> attn -> add, 16 rows per block.
// 256 threads = 4 waves.
// ---------------------------------------------------------------------------
__global__ __launch_bounds__(256, 3) void afd_main_kernel(const float* __restrict__ x,
                                                          float* __restrict__ out,
                                                          const ushort* __restrict__ b1h,
                                                          const ushort* __restrict__ b1l,
                                                          const ushort* __restrict__ b2h) {
    union SMem {
        struct {
            float xbuf[2][16][260];   // k-chunk staging, +4 pad vs bank conflicts
            float projp[4][16][68];   // split-K partials
        } g1;
        float ctile[16][268];          // GEMM2 epilogue tile (+12 pad)
    };
    __shared__ SMem sm;
    __shared__ __align__(16) ushort wbf[16][64];
    __shared__ float red[16][16];
    __shared__ float rowstat[16];

    const int tid  = threadIdx.x;
    const int wave = tid >> 6;
    const int lane = tid & 63;
    const int l16  = lane & 15;
    const int q    = lane >> 4;
    const int rb   = blockIdx.x * 16;
    const int srow = wave * 4;          // rows this wave stages / RMWs

    // ---------------- GEMM1: LDS-staged x, split-K across waves -----------
    // Staging: chunk c = 256 floats/row. Wave stages rows srow..srow+3,
    // 1 KB contiguous per instruction.
    const float* xsrc = x + (size_t)(rb + srow) * L_DIM + lane * 4;

    f32x4 st[4];
#pragma unroll
    for (int rr = 0; rr < 4; ++rr)
        st[rr] = *(const f32x4*)(xsrc + (size_t)rr * L_DIM);
#pragma unroll
    for (int rr = 0; rr < 4; ++rr)
        *(f32x4*)&sm.g1.xbuf[0][srow + rr][lane * 4] = st[rr];
#pragma unroll
    for (int rr = 0; rr < 4; ++rr)
        st[rr] = *(const f32x4*)(xsrc + (size_t)rr * L_DIM + 256);
    asm volatile("s_waitcnt lgkmcnt(0)" ::: "memory");
    __builtin_amdgcn_s_barrier();

    f32x4 acc[3][4];   // [chain hh/hl/lh][n-tile]
#pragma unroll
    for (int ch = 0; ch < 3; ++ch)
#pragma unroll
        for (int t = 0; t < 4; ++t) acc[ch][t] = (f32x4){0.f, 0.f, 0.f, 0.f};

    const ushort* bh_base = b1h + l16 * 8 + q * 512;
    const ushort* bl_base = b1l + l16 * 8 + q * 512;
    const int koff = wave * 64 + q * 8;      // within-chunk read offset

#pragma unroll 1
    for (int c = 0; c < 16; ++c) {
        const int buf = c & 1;
        // compute this chunk: 2 k-steps of 32, all 4 n-tiles, 3 chains
#pragma unroll
        for (int ks = 0; ks < 2; ++ks) {
            const int k0 = c * 256 + wave * 64 + ks * 32;   // absolute k
            f32x4 x0 = *(const f32x4*)&sm.g1.xbuf[buf][l16][koff + ks * 32];
            f32x4 x1 = *(const f32x4*)&sm.g1.xbuf[buf][l16][koff + ks * 32 + 4];
            s16x8 xh, xl;
#pragma unroll
            for (int j = 0; j < 4; ++j) {
                ushort h0 = f2bf(x0[j]);
                xh[j] = (short)h0;
                xl[j] = (short)f2bf(x0[j] - bf2f(h0));
                ushort h1 = f2bf(x1[j]);
                xh[4 + j] = (short)h1;
                xl[4 + j] = (short)f2bf(x1[j] - bf2f(h1));
            }
            const ushort* bh = bh_base + ((size_t)k0 << 6);
            const ushort* bl = bl_base + ((size_t)k0 << 6);
#pragma unroll
            for (int t = 0; t < 4; ++t) {
                s16x8 vh = *(const s16x8*)(bh + t * 128);
                s16x8 vl = *(const s16x8*)(bl + t * 128);
                acc[0][t] = MFMA16(xh, vh, acc[0][t]);
                acc[1][t] = MFMA16(xh, vl, acc[1][t]);
                acc[2][t] = MFMA16(xl, vh, acc[2][t]);
            }
        }
        if (c < 15) {
            // write staged chunk c+1 into the other buffer (safe: last read
            // of that buffer ended before the barrier that started chunk c)
#pragma unroll
            for (int rr = 0; rr < 4; ++rr)
                *(f32x4*)&sm.g1.xbuf[buf ^ 1][srow + rr][lane * 4] = st[rr];
            if (c < 14) {
#pragma unroll
                for (int rr = 0; rr < 4; ++rr)
                    st[rr] = *(const f32x4*)(xsrc + (size_t)rr * L_DIM + (c + 2) * 256);
            }
            asm volatile("s_waitcnt lgkmcnt(0)" ::: "memory");
            __builtin_amdgcn_s_barrier();
        }
    }

    // C layout: col = lane&15 (= n within tile), row = q*4 + reg
#pragma unroll
    for (int t = 0; t < 4; ++t) {
        f32x4 p = acc[0][t] + (acc[1][t] + acc[2][t]);
#pragma unroll
        for (int r = 0; r < 4; ++r)
            sm.g1.projp[wave][q * 4 + r][t * 16 + l16] = p[r];
    }
    __syncthreads();

    // ---------------- softmax(|proj|) over n=64, per row ------------------
    {
        const int row = tid >> 4;       // 16 rows
        const int i   = tid & 15;       // 16 segments of 4 n each
        f32x4 s = *(const f32x4*)&sm.g1.projp[0][row][i * 4];
        s += *(const f32x4*)&sm.g1.projp[1][row][i * 4];
        s += *(const f32x4*)&sm.g1.projp[2][row][i * 4];
        s += *(const f32x4*)&sm.g1.projp[3][row][i * 4];
        float a0 = fabsf(s[0]), a1 = fabsf(s[1]);
        float a2 = fabsf(s[2]), a3 = fabsf(s[3]);
        red[row][i] = fmaxf(fmaxf(a0, a1), fmaxf(a2, a3));
        __syncthreads();
        if (tid < 16) {
            float rm = red[tid][0];
#pragma unroll
            for (int j = 1; j < 16; ++j) rm = fmaxf(rm, red[tid][j]);
            rowstat[tid] = rm;
        }
        __syncthreads();
        float rm = rowstat[row];
        float e0 = __expf(a0 - rm), e1 = __expf(a1 - rm);
        float e2 = __expf(a2 - rm), e3 = __expf(a3 - rm);
        red[row][i] = e0 + e1 + e2 + e3;
        __syncthreads();
        if (tid < 16) {
            float ss = red[tid][0];
#pragma unroll
            for (int j = 1; j < 16; ++j) ss += red[tid][j];
            rowstat[tid] = 1.0f / ss;
        }
        __syncthreads();
        float inv = rowstat[row];
        wbf[row][i * 4 + 0] = f2bf(e0 * inv);
        wbf[row][i * 4 + 1] = f2bf(e1 * inv);
        wbf[row][i * 4 + 2] = f2bf(e2 * inv);
        wbf[row][i * 4 + 3] = f2bf(e3 * inv);
    }
    __syncthreads();

    // ---------------- GEMM2: out = x + W * B (contiguous epilogue) --------
    s16x8 a0f = *(const s16x8*)&wbf[l16][q * 8];
    s16x8 a1f = *(const s16x8*)&wbf[l16][32 + q * 8];
    const f32x4 zero = {0.f, 0.f, 0.f, 0.f};
    const ushort* b2p = b2h + (q * 4096 + l16) * 8;
    const float* xep = x   + (size_t)(rb + srow) * L_DIM + lane * 4;
    float*       oep = out + (size_t)(rb + srow) * L_DIM + lane * 4;

#pragma unroll 1
    for (int lc = 0; lc < 16; ++lc) {
        // prefetch this chunk's x (consumed after the mid barrier)
        f32x4 xr[4];
#pragma unroll
        for (int rr = 0; rr < 4; ++rr)
            xr[rr] = *(const f32x4*)(xep + (size_t)rr * L_DIM + lc * 256);

        // compute C for 4 l-tiles of 16, write to ctile
#pragma unroll
        for (int t = 0; t < 4; ++t) {
            const int l0 = lc * 256 + wave * 64 + t * 16;
            s16x8 b0  = *(const s16x8*)(b2p + (l0 << 3));
            s16x8 b1v = *(const s16x8*)(b2p + 131072 + (l0 << 3));   // n += 32
            f32x4 cfr = MFMA16(a0f, b0, zero);
            cfr = MFMA16(a1f, b1v, cfr);
#pragma unroll
            for (int r = 0; r < 4; ++r)
                sm.ctile[q * 4 + r][wave * 64 + t * 16 + l16] = cfr[r];
        }
        asm volatile("s_waitcnt lgkmcnt(0)" ::: "memory");
        __builtin_amdgcn_s_barrier();

        // cooperative RMW: wave owns rows srow..srow+3, 1 KB contiguous each
#pragma unroll
        for (int rr = 0; rr < 4; ++rr) {
            f32x4 cc = *(const f32x4*)&sm.ctile[srow + rr][lane * 4];
            f32x4 ov = xr[rr] + cc;
            *(f32x4*)(oep + (size_t)rr * L_DIM + lc * 256) = ov;
        }
        asm volatile("s_waitcnt lgkmcnt(0)" ::: "memory");
        __builtin_amdgcn_s_barrier();
    }
}

// ---------------------------------------------------------------------------
extern "C" void kernel_launch(void* const* d_in, const int* in_sizes, int n_in,
                              void* d_out, int out_size, void* d_ws, size_t ws_size,
                              hipStream_t stream) {
    const float* x = (const float*)d_in[0];
    float* out = (float*)d_out;

    // workspace: 3 pre-swizzled basis arrays, 64*4096 bf16 each (512 KiB each)
    ushort* b1h = (ushort*)d_ws;
    ushort* b1l = b1h + (size_t)N_BASIS * L_DIM;
    ushort* b2h = b1l + (size_t)N_BASIS * L_DIM;

    // ws is re-poisoned before every launch -> rebuild basis every call
    afd_basis_kernel<<<(N_BASIS * L_DIM) / 256, 256, 0, stream>>>(b1h, b1l, b2h);
    afd_main_kernel<<<BC / 16, 256, 0, stream>>>(x, out, b1h, b1l, b2h);
}